// Round 6
// baseline (71.704 us; speedup 1.0000x reference)
//
#include <hip/hip_runtime.h>
#include <hip/hip_fp16.h>
#include <math.h>

#define N_IMG 512
#define N_ANGLES 25
#define N_DET 512
#define DET_SPACING 3.0f
#define SRC_DIST 512.0f
#define DET_DIST 512.0f
#define N_SAMPLES 1024
#define PAD 8
#define QW 528            // padded grid side: r,c in [-8, 519]
#define NBC 132           // block-cols (QW/4)
#define BLK_STRIDE 4224   // one block-row of blocks = NBC*32 elements

// ---------------------------------------------------------------------------
// ws: 557 KB zero-padded FP16 PIXEL array, blocked 8(rows)x4(cols) pixels
// per 64 B cache line.  NO corner duplication (the quad array stored every
// pixel 4x, so a line only covered a 3x5-px footprint).
//   idx(R,C) = ((R>>3)*NBC + (C>>2))*32 + (R&7)*4 + (C&3)
//   New-line rate per sample: |dr|/8 + |dc|/4  ~= 0.25-0.28  (R3 quad: 0.50).
//
// Calibrated model (R0/R2/R3/R5 A/Bs): fanbeam cost tracks the UNION of
// unique 64B lines per 64-sample batch (~1 us per line-per-batch-equiv);
// gather-instruction count is ~free when the extra instrs hit already-
// resident lines (R2: 2 gathers same-lines == 1 gather).  Hence 4 ushort
// corner-gathers here: corner (0,0) pays the fresh line; (0,1),(1,0),(1,1)
// are same/adjacent-line L1 hits.  Neighbor offsets via 2 cndmasks/sample
// pair (block-crossing: col +1 -> +29 at C&3==3 else +1; row +1 -> +4196 at
// R&7==7 else +4).  fp16 values and bilinear fma order identical to R3 ->
// absmax stays exactly 0.25.
// Geometry: R3-measured-best (3200x256; R4 proved 1-wave blocks are worse).
// ---------------------------------------------------------------------------

__device__ __forceinline__ int pidx(int R, int C) {
    return (((R >> 3) * NBC + (C >> 2)) << 5) + ((R & 7) << 2) + (C & 3);
}

__device__ __forceinline__ float img_at(const float* __restrict__ img, int r, int c) {
    return ((unsigned)r < N_IMG && (unsigned)c < N_IMG) ? img[(r << 9) + c] : 0.0f;
}

__global__ __launch_bounds__(256) void build_px16(const float* __restrict__ img,
                                                  __half* __restrict__ px) {
    int idx = blockIdx.x * 256 + (int)threadIdx.x;
    if (idx >= QW * QW) return;
    int R = idx / QW, C = idx - R * QW;
    px[pidx(R, C)] = __float2half_rn(img_at(img, R - PAD, C - PAD));
}

// Clip [tlo,thi] to { t : lo <= v0 + t*dv <= hi }.
__device__ __forceinline__ void slab(float v0, float dv, float lo, float hi,
                                     float& tlo, float& thi) {
    if (fabsf(dv) < 1e-8f) {
        if (v0 < lo || v0 > hi) { tlo = 1.0f; thi = 0.0f; }
    } else {
        float inv = 1.0f / dv;
        float ta = (lo - v0) * inv;
        float tb = (hi - v0) * inv;
        tlo = fmaxf(tlo, fminf(ta, tb));
        thi = fminf(thi, fmaxf(ta, tb));
    }
}

// Bilinear from 4 separately-gathered fp16 corners; fma order == R3's bil16.
__device__ __forceinline__ float bil4(float v00, float v01, float v10, float v11,
                                      float fc, float fr) {
    float tv = fmaf(fc, v01 - v00, v00);
    float bv = fmaf(fc, v11 - v10, v10);
    return fmaf(fr, bv - tv, tv);
}

__device__ __forceinline__ float sample_px(const __half* __restrict__ px,
                                           float col, float row) {
    float cf = floorf(col), rf = floorf(row);
    float fc = col - cf,    fr = row - rf;
    int R = (int)rf, C = (int)cf;
    int base = pidx(R, C);
    int dc = ((C & 3) == 3) ? 29   : 1;   // +1 col, handling 4-col block edge
    int dr = ((R & 7) == 7) ? 4196 : 4;   // +1 row, handling 8-row block edge
                                          // (BLK_STRIDE - 7*4 = 4224-28)
    float v00 = __half2float(px[base]);
    float v01 = __half2float(px[base + dc]);
    float v10 = __half2float(px[base + dr]);
    float v11 = __half2float(px[base + dr + dc]);
    return bil4(v00, v01, v10, v11, fc, fr);
}

// One wave per ray; 4-deep batched gathers; clamp-free padded inner loop.
__global__ __launch_bounds__(256) void fanbeam_kernel(const __half* __restrict__ px,
                                                      float* __restrict__ out) {
    const int gid  = blockIdx.x * 256 + (int)threadIdx.x;
    const int ray  = gid >> 6;
    const int lane = (int)threadIdx.x & 63;
    if (ray >= N_ANGLES * N_DET) return;

    const int a = ray >> 9;
    const int d = ray & 511;

    float beta = (2.0f * (float)a / 25.0f) * 3.14159265358979323846f;
    float c, s;
    __sincosf(beta, &s, &c);
    float t = ((float)d - (N_DET - 1) * 0.5f) * DET_SPACING;
    float srcx = -SRC_DIST * s;
    float srcy =  SRC_DIST * c;
    float dx = (t * c + DET_DIST * s) - srcx;
    float dy = (t * s - DET_DIST * c) - srcy;
    float seg = sqrtf(dx * dx + dy * dy);

    const float half_ = (N_IMG - 1) * 0.5f;
    const float col0 = srcx + half_;           // unpadded (for clipping)
    const float row0 = half_ - srcy;
    const float drow = -dy;
    const float col0p = col0 + (float)PAD;     // padded-coordinate origins
    const float row0p = row0 + (float)PAD;
    const float inv_n = 1.0f / N_SAMPLES;

    float tA = 0.0f, tB = 1.0f;
    slab(col0, dx,   -1.01f, 512.01f, tA, tB);
    slab(row0, drow, -1.01f, 512.01f, tA, tB);

    float acc = 0.0f;
    if (tA <= tB) {
        int i_lo = max(0,             (int)floorf(tA * N_SAMPLES - 0.5f) - 1);
        int i_hi = min(N_SAMPLES - 1, (int)ceilf (tB * N_SAMPLES - 0.5f) + 1);
        int n = i_hi - i_lo + 1;                       // wave-uniform
        int k = 0;
        // 4-deep batches: 16 independent ushort gathers in flight; padded
        // coords are always >= ~5 within the window -> trunc == floor, no clamps.
        for (; k + 256 <= n; k += 256) {
            float f0 = (float)(i_lo + k + lane);       // exact in fp32
            float acc4 = 0.0f;
            #pragma unroll
            for (int j = 0; j < 4; ++j) {
                float ts  = (f0 + (64.0f * j + 0.5f)) * inv_n;
                float col = fmaf(ts, dx,   col0p);
                float row = fmaf(ts, drow, row0p);
                acc4 += sample_px(px, col, row);
            }
            acc += acc4;
        }
        // Tail (< 4 strides): plain loop, still clamp-free.
        #pragma unroll 2
        for (int i = i_lo + k + lane; i <= i_hi; i += 64) {
            float ts  = ((float)i + 0.5f) * inv_n;
            float col = fmaf(ts, dx,   col0p);
            float row = fmaf(ts, drow, row0p);
            acc += sample_px(px, col, row);
        }
    }

    #pragma unroll
    for (int off = 32; off > 0; off >>= 1)
        acc += __shfl_down(acc, off, 64);

    if (lane == 0) out[ray] = acc * (seg * inv_n);
}

extern "C" void kernel_launch(void* const* d_in, const int* in_sizes, int n_in,
                              void* d_out, int out_size, void* d_ws, size_t ws_size,
                              hipStream_t stream) {
    const float* img = (const float*)d_in[0];
    float* out = (float*)d_out;
    __half* px = (__half*)d_ws;                    // 528*528*2 B = 557 KB

    build_px16<<<(QW * QW + 255) / 256, 256, 0, stream>>>(img, px);

    const int n_rays = N_ANGLES * N_DET;           // 12800 rays, 1 wave each
    fanbeam_kernel<<<n_rays * 64 / 256, 256, 0, stream>>>(px, out);
}

// Round 7
// 66.750 us; speedup vs baseline: 1.0742x; 1.0742x over previous
//
#include <hip/hip_runtime.h>
#include <hip/hip_fp16.h>
#include <math.h>

#define N_IMG 512
#define N_ANGLES 25
#define N_DET 512
#define DET_SPACING 3.0f
#define SRC_DIST 512.0f
#define DET_DIST 512.0f
#define N_SAMPLES 1024
#define PAD 8
#define QW 528            // padded grid side: r,c in [-8, 519]
#define NGC 132           // column groups of 4 (QW/4)

// ---------------------------------------------------------------------------
// ws: 2.23 MB zero-padded FP16 QUAD array, 2(rows)x4(cols) quads per 64 B
// line — EXACTLY the R3 layout (best measured: 66.3 us).
//
// R7 change: RAY-PACKED WAVES.  R6 established the TA model: cost ~ sum over
// gather INSTRUCTIONS of unique-lines-per-instruction (R2's "free" 2nd load
// was really a compiler-merged dwordx4 -> all good kernels were 1 gather
// instr/sample).  In R3 one instruction's 64 addresses = 64 consecutive
// samples of ONE ray = a 68-px streak ~ 34 lines.  Here one wave handles 4
// ADJACENT rays (same angle, detectors d..d+3) with 16 lanes each, so an
// instruction's addresses form a compact ~17x6 px patch ~ 10-14 lines
// (~2.7x fewer), same instruction count, same layout, same fp16 values.
// Per-ray sample windows differ by a few strides -> wave-union window +
// per-lane predication (addr cndmask to 0 + contrib cndmask to 0).
// Reduction: width-16 shuffle tree; lane 0 of each group writes its ray.
// Per-sample arithmetic bit-identical to R3; only fp32 sum grouping changes.
// ---------------------------------------------------------------------------

__device__ __forceinline__ int qidx16(int R, int C) {
    return (((R >> 1) * NGC + (C >> 2)) << 3) + ((R & 1) << 2) + (C & 3);
}

__device__ __forceinline__ float img_at(const float* __restrict__ img, int r, int c) {
    return ((unsigned)r < N_IMG && (unsigned)c < N_IMG) ? img[(r << 9) + c] : 0.0f;
}

__global__ __launch_bounds__(256) void build_quads16(const float* __restrict__ img,
                                                     uint2* __restrict__ quad) {
    int idx = blockIdx.x * 256 + (int)threadIdx.x;
    if (idx >= QW * QW) return;
    int R = idx / QW, C = idx - R * QW;
    int r = R - PAD, c = C - PAD;
    __half2 tp = __floats2half2_rn(img_at(img, r,     c), img_at(img, r,     c + 1));
    __half2 bt = __floats2half2_rn(img_at(img, r + 1, c), img_at(img, r + 1, c + 1));
    uint2 q;
    q.x = *reinterpret_cast<unsigned int*>(&tp);
    q.y = *reinterpret_cast<unsigned int*>(&bt);
    quad[qidx16(R, C)] = q;
}

// Clip [tlo,thi] to { t : lo <= v0 + t*dv <= hi }.
__device__ __forceinline__ void slab(float v0, float dv, float lo, float hi,
                                     float& tlo, float& thi) {
    if (fabsf(dv) < 1e-8f) {
        if (v0 < lo || v0 > hi) { tlo = 1.0f; thi = 0.0f; }
    } else {
        float inv = 1.0f / dv;
        float ta = (lo - v0) * inv;
        float tb = (hi - v0) * inv;
        tlo = fmaxf(tlo, fminf(ta, tb));
        thi = fminf(thi, fmaxf(ta, tb));
    }
}

__device__ __forceinline__ float bil16(uint2 q, float fc, float fr) {
    float2 top = __half22float2(*reinterpret_cast<__half2*>(&q.x));
    float2 bot = __half22float2(*reinterpret_cast<__half2*>(&q.y));
    float tv = fmaf(fc, top.y - top.x, top.x);
    float bv = fmaf(fc, bot.y - bot.x, bot.x);
    return fmaf(fr, bv - tv, tv);
}

// 4 waves/block, each wave = 4 adjacent rays x 16 lanes.  16 rays/block.
__global__ __launch_bounds__(256) void fanbeam_kernel(const uint2* __restrict__ quad,
                                                      float* __restrict__ out) {
    const int tid    = (int)threadIdx.x;
    const int lane16 = tid & 15;
    const int ray    = blockIdx.x * 16 + (tid >> 4);   // grid = 800 exact

    const int a = ray >> 9;          // 512 % 16 == 0 -> wave never crosses angle
    const int d = ray & 511;

    float beta = (2.0f * (float)a / 25.0f) * 3.14159265358979323846f;
    float c, s;
    __sincosf(beta, &s, &c);
    float t = ((float)d - (N_DET - 1) * 0.5f) * DET_SPACING;
    float srcx = -SRC_DIST * s;
    float srcy =  SRC_DIST * c;
    float dx = (t * c + DET_DIST * s) - srcx;
    float dy = (t * s - DET_DIST * c) - srcy;
    float seg = sqrtf(dx * dx + dy * dy);

    const float half_ = (N_IMG - 1) * 0.5f;
    const float col0 = srcx + half_;           // unpadded (for clipping)
    const float row0 = half_ - srcy;
    const float drow = -dy;
    const float col0p = col0 + (float)PAD;     // padded-coordinate origins
    const float row0p = row0 + (float)PAD;
    const float inv_n = 1.0f / N_SAMPLES;

    float tA = 0.0f, tB = 1.0f;
    slab(col0, dx,   -1.01f, 512.01f, tA, tB);
    slab(row0, drow, -1.01f, 512.01f, tA, tB);

    // Per-ray window (uniform within each 16-lane group); miss -> [1,0].
    int i_lo = 1, i_hi = 0;
    if (tA <= tB) {
        i_lo = max(0,             (int)floorf(tA * N_SAMPLES - 0.5f) - 1);
        i_hi = min(N_SAMPLES - 1, (int)ceilf (tB * N_SAMPLES - 0.5f) + 1);
    }

    // Wave-union window across the 4 ray-groups (xor over group-id bits).
    int lo_w = i_lo, hi_w = i_hi;
    lo_w = min(lo_w, __shfl_xor(lo_w, 16, 64));
    hi_w = max(hi_w, __shfl_xor(hi_w, 16, 64));
    lo_w = min(lo_w, __shfl_xor(lo_w, 32, 64));
    hi_w = max(hi_w, __shfl_xor(hi_w, 32, 64));

    float acc = 0.0f;
    // Each k-iter: 64 samples/ray, as 4 gathers of 16 consecutive samples.
    // Per gather instruction: 4 rays x 16 samples = compact patch.
    for (int k = lo_w; k <= hi_w; k += 64) {
        #pragma unroll
        for (int j = 0; j < 4; ++j) {
            int i = k + j * 16 + lane16;
            bool valid = (i >= i_lo) && (i <= i_hi);
            float ts  = ((float)i + 0.5f) * inv_n;
            float col = fmaf(ts, dx,   col0p);
            float row = fmaf(ts, drow, row0p);
            float cf = floorf(col), rf = floorf(row);
            float fc = col - cf,    fr = row - rf;
            int idx = valid ? qidx16((int)rf, (int)cf) : 0;
            uint2 q = quad[idx];
            float v = bil16(q, fc, fr);
            acc += valid ? v : 0.0f;
        }
    }

    // Width-16 reduce within each ray group.
    #pragma unroll
    for (int off = 8; off > 0; off >>= 1)
        acc += __shfl_down(acc, off, 16);

    if (lane16 == 0) out[ray] = acc * (seg * inv_n);
}

extern "C" void kernel_launch(void* const* d_in, const int* in_sizes, int n_in,
                              void* d_out, int out_size, void* d_ws, size_t ws_size,
                              hipStream_t stream) {
    const float* img = (const float*)d_in[0];
    float* out = (float*)d_out;
    uint2* quad = (uint2*)d_ws;                    // 528*528*8 B = 2.23 MB

    build_quads16<<<(QW * QW + 255) / 256, 256, 0, stream>>>(img, quad);

    const int n_rays = N_ANGLES * N_DET;           // 12800 rays, 16 per block
    fanbeam_kernel<<<n_rays / 16, 256, 0, stream>>>(quad, out);
}

// Round 8
// 65.784 us; speedup vs baseline: 1.0900x; 1.0147x over previous
//
#include <hip/hip_runtime.h>
#include <hip/hip_fp16.h>
#include <math.h>

#define N_IMG 512
#define N_ANGLES 25
#define N_DET 512
#define DET_SPACING 3.0f
#define SRC_DIST 512.0f
#define DET_DIST 512.0f
#define N_SAMPLES 1024
#define PAD 8
#define QW 528            // padded grid side: r,c in [-8, 519]
#define NGC 132           // column groups of 4 (QW/4)

// ---------------------------------------------------------------------------
// FINAL (R8 = revert to R3, best measured: 66.27 us).
// ws: 2.23 MB zero-padded FP16 QUAD array, 2(rows)x4(cols) quads per 64 B
// line.  quad16(R,C) = half{v(r,c), v(r,c+1), v(r+1,c), v(r+1,c+1)} in 8 B.
//   idx = ((R>>1)*NGC + (C>>2))*8 + (R&1)*4 + (C&3)
//
// Session evidence (R0-R7 A/Bs):
//  - fp16 quad blocking (R3): -5 us — unique-line traffic halved.  WIN.
//  - 1-wave blocks (R4): +1.3 us — occupancy already saturated.  REVERTED.
//  - dual direction-picked copies (R5): +3.3 us — build cost + L2.  REVERTED.
//  - 4 scalar corner gathers (R6): +5.4 us — TA is per-instruction.  REVERTED.
//  - 4-ray-packed waves (R7): +0.5 us — TA lines NOT the binding pipe.  REVERTED.
// Conclusion: fanbeam is VALU-bound (~7.4M samples x ~27 ops ≈ 10 us) with
// TA ~6 us hidden under it; fill poison (41.5 us, 81% HBM peak) dominates
// the total and is at its own roofline.  Remaining modeled headroom <= 3%.
// ---------------------------------------------------------------------------

__device__ __forceinline__ int qidx16(int R, int C) {
    return (((R >> 1) * NGC + (C >> 2)) << 3) + ((R & 1) << 2) + (C & 3);
}

__device__ __forceinline__ float img_at(const float* __restrict__ img, int r, int c) {
    return ((unsigned)r < N_IMG && (unsigned)c < N_IMG) ? img[(r << 9) + c] : 0.0f;
}

__global__ __launch_bounds__(256) void build_quads16(const float* __restrict__ img,
                                                     uint2* __restrict__ quad) {
    int idx = blockIdx.x * 256 + (int)threadIdx.x;
    if (idx >= QW * QW) return;
    int R = idx / QW, C = idx - R * QW;
    int r = R - PAD, c = C - PAD;
    __half2 tp = __floats2half2_rn(img_at(img, r,     c), img_at(img, r,     c + 1));
    __half2 bt = __floats2half2_rn(img_at(img, r + 1, c), img_at(img, r + 1, c + 1));
    uint2 q;
    q.x = *reinterpret_cast<unsigned int*>(&tp);
    q.y = *reinterpret_cast<unsigned int*>(&bt);
    quad[qidx16(R, C)] = q;
}

// Clip [tlo,thi] to { t : lo <= v0 + t*dv <= hi }.
__device__ __forceinline__ void slab(float v0, float dv, float lo, float hi,
                                     float& tlo, float& thi) {
    if (fabsf(dv) < 1e-8f) {
        if (v0 < lo || v0 > hi) { tlo = 1.0f; thi = 0.0f; }
    } else {
        float inv = 1.0f / dv;
        float ta = (lo - v0) * inv;
        float tb = (hi - v0) * inv;
        tlo = fmaxf(tlo, fminf(ta, tb));
        thi = fminf(thi, fmaxf(ta, tb));
    }
}

__device__ __forceinline__ float bil16(uint2 q, float fc, float fr) {
    float2 top = __half22float2(*reinterpret_cast<__half2*>(&q.x));
    float2 bot = __half22float2(*reinterpret_cast<__half2*>(&q.y));
    float tv = fmaf(fc, top.y - top.x, top.x);
    float bv = fmaf(fc, bot.y - bot.x, bot.x);
    return fmaf(fr, bv - tv, tv);
}

// One wave per ray; 4-deep batched loads; clamp-free padded inner loop.
__global__ __launch_bounds__(256) void fanbeam_kernel(const uint2* __restrict__ quad,
                                                      float* __restrict__ out) {
    const int gid  = blockIdx.x * 256 + (int)threadIdx.x;
    const int ray  = gid >> 6;
    const int lane = (int)threadIdx.x & 63;
    if (ray >= N_ANGLES * N_DET) return;

    const int a = ray >> 9;
    const int d = ray & 511;

    float beta = (2.0f * (float)a / 25.0f) * 3.14159265358979323846f;
    float c, s;
    __sincosf(beta, &s, &c);
    float t = ((float)d - (N_DET - 1) * 0.5f) * DET_SPACING;
    float srcx = -SRC_DIST * s;
    float srcy =  SRC_DIST * c;
    float dx = (t * c + DET_DIST * s) - srcx;
    float dy = (t * s - DET_DIST * c) - srcy;
    float seg = sqrtf(dx * dx + dy * dy);

    const float half = (N_IMG - 1) * 0.5f;
    const float col0 = srcx + half;            // unpadded (for clipping)
    const float row0 = half - srcy;
    const float drow = -dy;
    const float col0p = col0 + (float)PAD;     // padded-coordinate origins
    const float row0p = row0 + (float)PAD;
    const float inv_n = 1.0f / N_SAMPLES;

    float tA = 0.0f, tB = 1.0f;
    slab(col0, dx,   -1.01f, 512.01f, tA, tB);
    slab(row0, drow, -1.01f, 512.01f, tA, tB);

    float acc = 0.0f;
    if (tA <= tB) {
        int i_lo = max(0,             (int)floorf(tA * N_SAMPLES - 0.5f) - 1);
        int i_hi = min(N_SAMPLES - 1, (int)ceilf (tB * N_SAMPLES - 0.5f) + 1);
        int n = i_hi - i_lo + 1;                       // wave-uniform
        int k = 0;
        // 4-deep batches: 4 independent dwordx2 gathers in flight; padded
        // coords are always >= ~5 within the window -> trunc == floor, no clamps.
        for (; k + 256 <= n; k += 256) {
            float f0 = (float)(i_lo + k + lane);       // exact in fp32
            float acc4 = 0.0f;
            #pragma unroll
            for (int j = 0; j < 4; ++j) {
                float ts  = (f0 + (64.0f * j + 0.5f)) * inv_n;
                float col = fmaf(ts, dx,   col0p);
                float row = fmaf(ts, drow, row0p);
                float cf = floorf(col), rf = floorf(row);
                float fc = col - cf,    fr = row - rf;
                uint2 q = quad[qidx16((int)rf, (int)cf)];
                acc4 += bil16(q, fc, fr);
            }
            acc += acc4;
        }
        // Tail (< 4 strides): plain loop, still clamp-free.
        #pragma unroll 2
        for (int i = i_lo + k + lane; i <= i_hi; i += 64) {
            float ts  = ((float)i + 0.5f) * inv_n;
            float col = fmaf(ts, dx,   col0p);
            float row = fmaf(ts, drow, row0p);
            float cf = floorf(col), rf = floorf(row);
            float fc = col - cf,    fr = row - rf;
            uint2 q = quad[qidx16((int)rf, (int)cf)];
            acc += bil16(q, fc, fr);
        }
    }

    #pragma unroll
    for (int off = 32; off > 0; off >>= 1)
        acc += __shfl_down(acc, off, 64);

    if (lane == 0) out[ray] = acc * (seg * inv_n);
}

extern "C" void kernel_launch(void* const* d_in, const int* in_sizes, int n_in,
                              void* d_out, int out_size, void* d_ws, size_t ws_size,
                              hipStream_t stream) {
    const float* img = (const float*)d_in[0];
    float* out = (float*)d_out;
    uint2* quad = (uint2*)d_ws;                    // 528*528*8 B = 2.23 MB

    build_quads16<<<(QW * QW + 255) / 256, 256, 0, stream>>>(img, quad);

    const int n_rays = N_ANGLES * N_DET;           // 12800 rays, 1 wave each
    fanbeam_kernel<<<n_rays * 64 / 256, 256, 0, stream>>>(quad, out);
}